// Round 4
// baseline (1922.773 us; speedup 1.0000x reference)
//
#include <hip/hip_runtime.h>
#include <cstdint>

#define TT 2048
#define CCH 1024
#define FFD 4096
#define EPSV 1e-5f
#define NCHK 32
#define CHKL 64   // TT / NCHK

typedef __attribute__((ext_vector_type(4))) float floatx4;
typedef __attribute__((ext_vector_type(8))) short shortx8;

__device__ __forceinline__ unsigned short f32_to_bf16(float f){
  union { float f; unsigned int u; } x; x.f = f;
  unsigned int r = x.u + 0x7fffu + ((x.u >> 16) & 1u);
  return (unsigned short)(r >> 16);
}
__device__ __forceinline__ float bf16_to_f32(unsigned short h){
  union { unsigned int u; float f; } x; x.u = ((unsigned int)h) << 16;
  return x.f;
}
__device__ __forceinline__ float wave_sum(float v){
  #pragma unroll
  for (int o = 32; o > 0; o >>= 1) v += __shfl_down(v, o, 64);
  return v;
}
__device__ __forceinline__ void async16(const void* g, void* l){
  __builtin_amdgcn_global_load_lds((const __attribute__((address_space(1))) void*)g,
                                   (__attribute__((address_space(3))) void*)l, 16, 0, 0);
}

// ---------------- fp32 -> bf16 weight conversion (7 segments fused) ----------------
struct CvtArgs {
  const float* s[7];
  unsigned short* d[7];
  int n4[7];
};
__global__ __launch_bounds__(256) void cvt7_kernel(CvtArgs a){
  const int seg = blockIdx.y;
  const float* __restrict__ s = a.s[seg];
  unsigned short* __restrict__ d = a.d[seg];
  const int n4 = a.n4[seg];
  for (int i = blockIdx.x * 256 + threadIdx.x; i < n4; i += gridDim.x * 256) {
    float4 v = ((const float4*)s)[i];
    union { unsigned short u[4]; uint2 p; } o;
    o.u[0] = f32_to_bf16(v.x); o.u[1] = f32_to_bf16(v.y);
    o.u[2] = f32_to_bf16(v.z); o.u[3] = f32_to_bf16(v.w);
    *(uint2*)&d[(long)i * 4] = o.p;
  }
}

// ---------------- ln0: x_in -> x (fp32) ----------------
__global__ __launch_bounds__(256) void ln0_kernel(const float* __restrict__ xin,
    const float* __restrict__ w, const float* __restrict__ b, float* __restrict__ xo){
  const int row = blockIdx.x, tid = threadIdx.x;
  const float* xr = xin + (long)row * CCH;
  float c4[4]; float s = 0.f, s2 = 0.f;
  #pragma unroll
  for (int j = 0; j < 4; j++){ c4[j] = xr[tid + j*256]; s += c4[j]; s2 += c4[j]*c4[j]; }
  s = wave_sum(s); s2 = wave_sum(s2);
  __shared__ float red[2][4];
  const int wid = tid >> 6, lane = tid & 63;
  if (lane == 0){ red[0][wid] = s; red[1][wid] = s2; }
  __syncthreads();
  const float S  = red[0][0]+red[0][1]+red[0][2]+red[0][3];
  const float S2 = red[1][0]+red[1][1]+red[1][2]+red[1][3];
  const float inv = 1.f / CCH;
  const float m = S * inv;
  const float rs = rsqrtf(S2 * inv - m*m + EPSV);
  float* xout = xo + (long)row * CCH;
  #pragma unroll
  for (int j = 0; j < 4; j++){ int c = tid + j*256; xout[c] = (c4[j]-m)*rs*w[c] + b[c]; }
}

// ---------------- fused LN + time-shift + mix -> bf16 ----------------
template<int NOUT>
__global__ __launch_bounds__(256) void ln_mix(
    const float* __restrict__ x,
    const float* __restrict__ lw, const float* __restrict__ lb,
    const float* __restrict__ mk, const float* __restrict__ mv, const float* __restrict__ mr,
    unsigned short* __restrict__ xk, unsigned short* __restrict__ xv, unsigned short* __restrict__ xr)
{
  const int row = blockIdx.x;
  const int t = row & (TT - 1);
  const int tid = threadIdx.x;
  const float* xc = x + (long)row * CCH;
  const float* xp = xc - CCH;
  float c4[4], p4[4];
  float s1=0.f, s2=0.f, s3=0.f, s4=0.f;
  #pragma unroll
  for (int j = 0; j < 4; j++){
    const int c = tid + j*256;
    c4[j] = xc[c];
    p4[j] = (t > 0) ? xp[c] : 0.f;
    s1 += c4[j]; s2 += c4[j]*c4[j];
    s3 += p4[j]; s4 += p4[j]*p4[j];
  }
  s1 = wave_sum(s1); s2 = wave_sum(s2); s3 = wave_sum(s3); s4 = wave_sum(s4);
  __shared__ float red[4][4];
  const int wid = tid >> 6, lane = tid & 63;
  if (lane == 0){ red[wid][0]=s1; red[wid][1]=s2; red[wid][2]=s3; red[wid][3]=s4; }
  __syncthreads();
  const float S1 = red[0][0]+red[1][0]+red[2][0]+red[3][0];
  const float S2 = red[0][1]+red[1][1]+red[2][1]+red[3][1];
  const float S3 = red[0][2]+red[1][2]+red[2][2]+red[3][2];
  const float S4 = red[0][3]+red[1][3]+red[2][3]+red[3][3];
  const float inv = 1.f / CCH;
  const float m1 = S1*inv; const float r1 = rsqrtf(S2*inv - m1*m1 + EPSV);
  const float m0 = S3*inv; const float r0 = rsqrtf(S4*inv - m0*m0 + EPSV);
  #pragma unroll
  for (int j = 0; j < 4; j++){
    const int c = tid + j*256;
    const long o = (long)row * CCH + c;
    const float wv = lw[c], bv = lb[c];
    const float h  = (c4[j]-m1)*r1*wv + bv;
    const float hp = (t > 0) ? ((p4[j]-m0)*r0*wv + bv) : 0.f;
    const float a = mk[c]; xk[o] = f32_to_bf16(h*a + hp*(1.f-a));
    if (NOUT == 3){ const float q = mv[c]; xv[o] = f32_to_bf16(h*q + hp*(1.f-q)); }
    const float g = mr[c]; xr[o] = f32_to_bf16(h*g + hp*(1.f-g));
  }
}

// ---------------- WKV blocked scan ----------------
__global__ __launch_bounds__(256) void wkv_pass1(
    const unsigned short* __restrict__ kin, const unsigned short* __restrict__ vin,
    const float* __restrict__ td,
    float* __restrict__ sta, float* __restrict__ stb, float* __restrict__ stp)
{
  const int c = blockIdx.x * 256 + threadIdx.x;
  const int chunk = blockIdx.y, b = blockIdx.z;
  const float w = -__expf(td[c]);
  const long base = ((long)b * TT + (long)chunk * CHKL) * CCH + c;
  float aa = 0.f, bb = 0.f, pp = -1e38f;
  for (int t0 = 0; t0 < CHKL; t0 += 8) {
    float kr[8], vr[8];
    #pragma unroll
    for (int j = 0; j < 8; j++){
      const long o = base + (long)(t0 + j) * CCH;
      kr[j] = bf16_to_f32(kin[o]);
      vr[j] = bf16_to_f32(vin[o]);
    }
    #pragma unroll
    for (int j = 0; j < 8; j++){
      const float kk = kr[j], vv = vr[j];
      const float ww2 = pp + w;
      const float qq2 = fmaxf(ww2, kk);
      const float e1b = __expf(ww2 - qq2), e2b = __expf(kk - qq2);
      aa = e1b*aa + e2b*vv; bb = e1b*bb + e2b; pp = qq2;
    }
  }
  const long si = (long)chunk * 4096 + b * CCH + c;
  sta[si] = aa; stb[si] = bb; stp[si] = pp;
}

__global__ __launch_bounds__(256) void wkv_combine(
    const float* __restrict__ td,
    const float* __restrict__ sta, const float* __restrict__ stb, const float* __restrict__ stp,
    float* __restrict__ ina, float* __restrict__ inb, float* __restrict__ inp)
{
  const int idx = blockIdx.x * 256 + threadIdx.x;   // b*C + c
  const int c = idx & (CCH - 1);
  const float wn = -__expf(td[c]) * (float)CHKL;
  float a = 0.f, b = 0.f, p = -1e38f;
  for (int j0 = 0; j0 < NCHK; j0 += 8) {
    float la[8], lb[8], lp[8];
    #pragma unroll
    for (int j = 0; j < 8; j++){
      const long si = (long)(j0 + j) * 4096 + idx;
      la[j] = sta[si]; lb[j] = stb[si]; lp[j] = stp[si];
    }
    #pragma unroll
    for (int j = 0; j < 8; j++){
      const long si = (long)(j0 + j) * 4096 + idx;
      ina[si] = a; inb[si] = b; inp[si] = p;
      const float pd = p + wn;
      const float q = fmaxf(pd, lp[j]);
      const float e1 = __expf(pd - q), e2 = __expf(lp[j] - q);
      a = e1*a + e2*la[j]; b = e1*b + e2*lb[j]; p = q;
    }
  }
}

__global__ __launch_bounds__(256) void wkv_pass2(
    const unsigned short* __restrict__ kin, const unsigned short* __restrict__ vin,
    const unsigned short* __restrict__ srin,
    const float* __restrict__ td, const float* __restrict__ tf,
    const float* __restrict__ ina, const float* __restrict__ inb, const float* __restrict__ inp,
    unsigned short* __restrict__ out)
{
  const int c = blockIdx.x * 256 + threadIdx.x;
  const int chunk = blockIdx.y, b = blockIdx.z;
  const float w = -__expf(td[c]);
  const float u = tf[c];
  const long si = (long)chunk * 4096 + b * CCH + c;
  float aa = ina[si], bb = inb[si], pp = inp[si];
  const long base = ((long)b * TT + (long)chunk * CHKL) * CCH + c;
  for (int t0 = 0; t0 < CHKL; t0 += 8) {
    float kr[8], vr[8], sr[8];
    #pragma unroll
    for (int j = 0; j < 8; j++){
      const long o = base + (long)(t0 + j) * CCH;
      kr[j] = bf16_to_f32(kin[o]);
      vr[j] = bf16_to_f32(vin[o]);
      sr[j] = bf16_to_f32(srin[o]);
    }
    #pragma unroll
    for (int j = 0; j < 8; j++){
      const float kk = kr[j], vv = vr[j];
      const float ww = u + kk;
      const float qq = fmaxf(pp, ww);
      const float e1 = __expf(pp - qq), e2 = __expf(ww - qq);
      const float outv = (e1*aa + e2*vv) / (e1*bb + e2);
      const float ww2 = pp + w;
      const float qq2 = fmaxf(ww2, kk);
      const float e1b = __expf(ww2 - qq2), e2b = __expf(kk - qq2);
      aa = e1b*aa + e2b*vv; bb = e1b*bb + e2b; pp = qq2;
      out[base + (long)(t0 + j) * CCH] = f32_to_bf16(sr[j] * outv);
    }
  }
}

// ---------------- bf16 MFMA GEMM: C[M,N] = A[M,K] * W[N,K]^T ----------------
// R9: R8's wide wave-tile (BMt=256 -> 40.6% MfmaUtil, matched prediction)
// + remove the per-K-step vmcnt(0) drain WITHOUT losing 2-block/CU
// residency (R6/R7 lesson): BK=32 with a 3-SLOT LDS ring.
//   LDS = (BMt+128)*32*2*3 = 72KB (BMt=256) / 48KB (BMt=128): 2 blocks/CU
//   (register-capped there anyway: 84 VGPR + 128 AGPR).
//   iter t: stage(t+2 -> slot (t+2)%3)  [distinct from slot t%3 being read]
//           ds_read frags from slot t%3; MFMA; vmcnt(LPT) [t+2 stays in
//           flight]; ONE barrier.
//   Race proof: slot (t+2)%3 was last read in iter t-1; end-of-(t-1) barrier
//   orders all waves' reads (each frag consumed by MFMA before barrier)
//   before any wave's iter-t staging. Counted vmcnt + barrier => tile t+1
//   resident for all waves. Tail drains LPT -> 0.
//   XOR swizzle (BK=32, 4 chunks): slot = chunk ^ (row&3); balanced 8
//   accesses per 4-bank group per ds_read_b128 (same balance as R4-proven
//   BK=64 pattern).
#define BK 32

enum { EP_BF16 = 0, EP_ADD = 3, EP_MULADD = 4, EP_KVR = 5, EP_FFN1 = 6 };

template<int EPI, int BMt>
__global__ __launch_bounds__(256, 2) void gemm_bt(
    const unsigned short* __restrict__ A,
    const unsigned short* __restrict__ W,
    int N, const int K,
    unsigned short* __restrict__ outb,
    float* __restrict__ xres,
    const unsigned short* __restrict__ rr,
    const unsigned short* __restrict__ A2,
    const unsigned short* __restrict__ W2,
    unsigned short* __restrict__ outb2,
    const int N2)
{
  constexpr int MR = BMt / 2 / 16;       // 8 (BMt=256) or 4 (BMt=128)
  constexpr int NR = 4;                  // BN=128, 2 col-waves
  constexpr int LA = BMt * 4 / 256;      // A-loads/thread/tile: 4 or 2
  constexpr int LB = 2;                  // B-loads/thread/tile
  constexpr int LPT = LA + LB;           // 6 or 4

  const int bm = blockIdx.x;
  int bn = blockIdx.y;
  bool sig = false;
  if (EPI == EP_KVR) {
    const long z = blockIdx.z;
    const long Mfull = (long)gridDim.x * BMt;
    A    += z * Mfull * K;
    W    += z * (long)N * K;
    outb += z * Mfull * N;
    sig = (blockIdx.z == 2);
  }
  if (EPI == EP_FFN1) {
    if (blockIdx.z == 1) {
      if (bn >= N2 / 128) return;   // block-uniform early-exit, before any barrier
      A = A2; W = W2; outb = outb2; N = N2; sig = true;
    }
  }
  __shared__ unsigned short lA[3][BMt * BK];   // 3 x 16/8 KB
  __shared__ unsigned short lW[3][128 * BK];   // 3 x 8 KB
  const int tid = threadIdx.x;
  const int wid = tid >> 6, lane = tid & 63;
  const int wm = (wid >> 1), wn = (wid & 1);
  const int quad = lane >> 4, r16 = lane & 15;
  const int WR = wm * (MR * 16);

  // staging: thread covers 16B-position P = i*256 + tid in the slot.
  // row = P>>2, stored slot-chunk = P&3, logical chunk = (P&3) ^ (row&3)
  // -> pre-swizzled GLOBAL source, linear LDS destination (rule #21).
  const unsigned short* aSrc[LA]; int aDst[LA];
  #pragma unroll
  for (int i = 0; i < LA; i++) {
    const int P = i * 256 + tid;
    const int row = P >> 2;
    const int c = (P & 3) ^ (row & 3);
    aSrc[i] = A + (long)(bm * BMt + row) * K + c * 8;
    aDst[i] = P * 8;
  }
  const unsigned short* bSrc[LB]; int bDst[LB];
  #pragma unroll
  for (int i = 0; i < LB; i++) {
    const int P = i * 256 + tid;
    const int row = P >> 2;
    const int c = (P & 3) ^ (row & 3);
    bSrc[i] = W + (long)(bn * 128 + row) * K + c * 8;
    bDst[i] = P * 8;
  }

  // fragment-read swizzle: logical chunk quad of row R lives at slot
  // quad ^ (R&3); R&3 == r16&3 for all frag rows (16-multiples added).
  const int swq = (quad ^ (r16 & 3)) * 8;

  const floatx4 zf = {0.f, 0.f, 0.f, 0.f};
  floatx4 acc[MR][NR];
  #pragma unroll
  for (int i = 0; i < MR; i++)
    #pragma unroll
    for (int j = 0; j < NR; j++) acc[i][j] = zf;

  const int NT = K / BK;

  // prologue: tiles 0,1 into slots 0,1; wait tile 0 (LPT of tile 1 in flight)
  #pragma unroll
  for (int tt = 0; tt < 2; ++tt) {
    const long ko = (long)tt * BK;
    #pragma unroll
    for (int i = 0; i < LA; i++) async16(aSrc[i] + ko, &lA[tt][aDst[i]]);
    #pragma unroll
    for (int i = 0; i < LB; i++) async16(bSrc[i] + ko, &lW[tt][bDst[i]]);
  }
  asm volatile("s_waitcnt vmcnt(%0)" :: "n"(LPT) : "memory");
  __builtin_amdgcn_s_barrier();
  __builtin_amdgcn_sched_barrier(0);

  int s = 0, s2 = 2;   // slot of tile t, slot of tile t+2
  for (int t = 0; t < NT; ++t) {
    // stage tile t+2 into slot s2 (last read in iter t-1; safe after barrier)
    if (t + 2 < NT) {
      const long ko = (long)(t + 2) * BK;
      #pragma unroll
      for (int i = 0; i < LA; i++) async16(aSrc[i] + ko, &lA[s2][aDst[i]]);
      #pragma unroll
      for (int i = 0; i < LB; i++) async16(bSrc[i] + ko, &lW[s2][bDst[i]]);
    }
    // fragments for tile t from slot s
    shortx8 af[MR], bf[NR];
    #pragma unroll
    for (int m = 0; m < MR; m++)
      af[m] = *(const shortx8*)&lA[s][(WR + m * 16 + r16) * BK + swq];
    #pragma unroll
    for (int n = 0; n < NR; n++)
      bf[n] = *(const shortx8*)&lW[s][(wn * 64 + n * 16 + r16) * BK + swq];
    __builtin_amdgcn_s_setprio(1);
    #pragma unroll
    for (int m = 0; m < MR; m++)
      #pragma unroll
      for (int n = 0; n < NR; n++)
        acc[m][n] = __builtin_amdgcn_mfma_f32_16x16x32_bf16(af[m], bf[n], acc[m][n], 0, 0, 0);
    __builtin_amdgcn_s_setprio(0);
    __builtin_amdgcn_sched_barrier(0);
    // counted wait: tile t+1 resident; tile t+2 stays in flight (never 0
    // mid-loop). Tail: drain LPT -> 0.
    if (t + 2 < NT)      asm volatile("s_waitcnt vmcnt(%0)" :: "n"(LPT) : "memory");
    else if (t + 1 < NT) asm volatile("s_waitcnt vmcnt(0)" ::: "memory");
    if (t + 1 < NT) {
      asm volatile("s_waitcnt lgkmcnt(0)" ::: "memory");
      __builtin_amdgcn_s_barrier();
      __builtin_amdgcn_sched_barrier(0);
    }
    s = (s == 2) ? 0 : s + 1;
    s2 = (s2 == 2) ? 0 : s2 + 1;
  }

  const int colBase = bn * 128 + wn * 64 + r16;
  #pragma unroll
  for (int m = 0; m < MR; m++) {
    const int rowBase = bm * BMt + WR + m * 16 + quad * 4;
    #pragma unroll
    for (int n = 0; n < NR; n++) {
      const int col = colBase + n * 16;
      #pragma unroll
      for (int r = 0; r < 4; r++) {
        const long idx = (long)(rowBase + r) * N + col;
        const float val = acc[m][n][r];
        if (EPI == EP_KVR)       outb[idx] = sig ? f32_to_bf16(1.f / (1.f + __expf(-val)))
                                                 : f32_to_bf16(val);
        else if (EPI == EP_FFN1) {
          if (sig) outb[idx] = f32_to_bf16(1.f / (1.f + __expf(-val)));
          else     { const float t = val > 0.f ? val : 0.f; outb[idx] = f32_to_bf16(t * t); }
        }
        else if (EPI == EP_ADD)  xres[idx] += val;
        else if (EPI == EP_MULADD) xres[idx] = fmaf(bf16_to_f32(rr[idx]), val, xres[idx]);
        else                     outb[idx] = f32_to_bf16(val);
      }
    }
  }
}

extern "C" void kernel_launch(void* const* d_in, const int* in_sizes, int n_in,
                              void* d_out, int out_size, void* d_ws, size_t ws_size,
                              hipStream_t stream)
{
  const float* x_in       = (const float*)d_in[0];
  const float* ln0_w      = (const float*)d_in[1];
  const float* ln0_b      = (const float*)d_in[2];
  const float* ln1_w      = (const float*)d_in[3];
  const float* ln1_b      = (const float*)d_in[4];
  const float* ln2_w      = (const float*)d_in[5];
  const float* ln2_b      = (const float*)d_in[6];
  const float* time_decay = (const float*)d_in[7];
  const float* time_first = (const float*)d_in[8];
  const float* tmk        = (const float*)d_in[9];
  const float* tmv        = (const float*)d_in[10];
  const float* tmr        = (const float*)d_in[11];
  const float* Wk         = (const float*)d_in[12];
  const float* Wv         = (const float*)d_in[13];
  const float* Wr         = (const float*)d_in[14];
  const float* Wo         = (const float*)d_in[15];
  const float* cmk        = (const float*)d_in[16];
  const float* cmr        = (const float*)d_in[17];
  const float* Wck        = (const float*)d_in[18];
  const float* Wcv        = (const float*)d_in[19];
  const float* Wcr        = (const float*)d_in[20];
  float* x = (float*)d_out;

  const int M = 4 * TT;                 // 8192 rows
  const long lCC = (long)CCH * CCH;
  const long lFC = (long)FFD * CCH;
  const long MC  = (long)M * CCH;

  unsigned short* wsl  = (unsigned short*)d_ws;
  unsigned short* wkb  = wsl;
  unsigned short* wvb  = wkb + lCC;
  unsigned short* wrb  = wvb + lCC;
  unsigned short* wob  = wrb + lCC;
  unsigned short* wcrb = wob + lCC;
  unsigned short* wckb = wcrb + lCC;
  unsigned short* wcvb = wckb + lFC;
  unsigned short* xk   = wcvb + lFC;
  unsigned short* xv   = xk + MC;
  unsigned short* xr   = xv + MC;
  unsigned short* kbuf = xr + MC;       // region reused as kf [M,F]
  unsigned short* vbuf = kbuf + MC;
  unsigned short* sbuf = vbuf + MC;
  unsigned short* kfb  = kbuf;
  unsigned short* rrb  = kbuf + (long)M * FFD;

  // WKV scan state in the (dead between GEMMs) xk region
  float* sta = (float*)xk;
  float* stb = sta + (long)NCHK * 4096;
  float* stp = stb + (long)NCHK * 4096;
  float* ina = stp + (long)NCHK * 4096;
  float* inb = ina + (long)NCHK * 4096;
  float* inp = inb + (long)NCHK * 4096;

  ln0_kernel<<<M, 256, 0, stream>>>(x_in, ln0_w, ln0_b, x);

  const dim3 gkvr(M / 256, CCH / 128, 3);  // (32, 8, 3)  = 768 blocks, BMt=256
  const dim3 g1  (M / 128, CCH / 128);     // (64, 8)     = 512 blocks, BMt=128
  const dim3 gffn(M / 256, FFD / 128, 2);  // (32, 32, 2), BMt=256; z1 = r sigmoid (bn<8)
  const dim3 gw(CCH / 256, NCHK, 4);       // (4, 32, 4)

  for (int l = 0; l < 4; l++) {
    CvtArgs ca;
    ca.s[0] = Wk  + (long)l * lCC; ca.d[0] = wkb;  ca.n4[0] = (int)(lCC / 4);
    ca.s[1] = Wv  + (long)l * lCC; ca.d[1] = wvb;  ca.n4[1] = (int)(lCC / 4);
    ca.s[2] = Wr  + (long)l * lCC; ca.d[2] = wrb;  ca.n4[2] = (int)(lCC / 4);
    ca.s[3] = Wo  + (long)l * lCC; ca.d[3] = wob;  ca.n4[3] = (int)(lCC / 4);
    ca.s[4] = Wcr + (long)l * lCC; ca.d[4] = wcrb; ca.n4[4] = (int)(lCC / 4);
    ca.s[5] = Wck + (long)l * lFC; ca.d[5] = wckb; ca.n4[5] = (int)(lFC / 4);
    ca.s[6] = Wcv + (long)l * lFC; ca.d[6] = wcvb; ca.n4[6] = (int)(lFC / 4);
    cvt7_kernel<<<dim3(512, 7), 256, 0, stream>>>(ca);

    const float* td_l = time_decay + l*CCH;
    const float* tf_l = time_first + l*CCH;

    // --- TimeMix ---
    ln_mix<3><<<M, 256, 0, stream>>>(x, ln1_w + l*CCH, ln1_b + l*CCH,
                                     tmk + l*CCH, tmv + l*CCH, tmr + l*CCH, xk, xv, xr);
    gemm_bt<EP_KVR, 256><<<gkvr, 256, 0, stream>>>(xk, wkb, CCH, CCH, kbuf, nullptr,
                                              nullptr, nullptr, nullptr, nullptr, 0);
    wkv_pass1 <<<gw, 256, 0, stream>>>(kbuf, vbuf, td_l, sta, stb, stp);
    wkv_combine<<<16, 256, 0, stream>>>(td_l, sta, stb, stp, ina, inb, inp);
    wkv_pass2 <<<gw, 256, 0, stream>>>(kbuf, vbuf, sbuf, td_l, tf_l, ina, inb, inp, xv);
    gemm_bt<EP_ADD, 128><<<g1, 256, 0, stream>>>(xv, wob, CCH, CCH, nullptr, x, nullptr,
                                             nullptr, nullptr, nullptr, 0);

    // --- ChannelMix ---
    ln_mix<2><<<M, 256, 0, stream>>>(x, ln2_w + l*CCH, ln2_b + l*CCH,
                                     cmk + l*CCH, nullptr, cmr + l*CCH, xk, nullptr, xr);
    gemm_bt<EP_FFN1, 256><<<gffn, 256, 0, stream>>>(xk, wckb, FFD, CCH, kfb, nullptr,
                                               nullptr, xr, wcrb, rrb, CCH);
    gemm_bt<EP_MULADD, 128><<<g1, 256, 0, stream>>>(kfb, wcvb, CCH, FFD, nullptr, x, rrb,
                                               nullptr, nullptr, nullptr, 0);
  }
}

// Round 5
// 1890.109 us; speedup vs baseline: 1.0173x; 1.0173x over previous
//
#include <hip/hip_runtime.h>
#include <cstdint>

#define TT 2048
#define CCH 1024
#define FFD 4096
#define EPSV 1e-5f
#define NCHK 32
#define CHKL 64   // TT / NCHK

typedef __attribute__((ext_vector_type(4))) float floatx4;
typedef __attribute__((ext_vector_type(8))) short shortx8;

__device__ __forceinline__ unsigned short f32_to_bf16(float f){
  union { float f; unsigned int u; } x; x.f = f;
  unsigned int r = x.u + 0x7fffu + ((x.u >> 16) & 1u);
  return (unsigned short)(r >> 16);
}
__device__ __forceinline__ float bf16_to_f32(unsigned short h){
  union { unsigned int u; float f; } x; x.u = ((unsigned int)h) << 16;
  return x.f;
}
__device__ __forceinline__ float wave_sum(float v){
  #pragma unroll
  for (int o = 32; o > 0; o >>= 1) v += __shfl_down(v, o, 64);
  return v;
}
__device__ __forceinline__ void async16(const void* g, void* l){
  __builtin_amdgcn_global_load_lds((const __attribute__((address_space(1))) void*)g,
                                   (__attribute__((address_space(3))) void*)l, 16, 0, 0);
}

// ---------------- fp32 -> bf16 weight conversion (7 segments fused) ----------------
struct CvtArgs {
  const float* s[7];
  unsigned short* d[7];
  int n4[7];
};
__global__ __launch_bounds__(256) void cvt7_kernel(CvtArgs a){
  const int seg = blockIdx.y;
  const float* __restrict__ s = a.s[seg];
  unsigned short* __restrict__ d = a.d[seg];
  const int n4 = a.n4[seg];
  for (int i = blockIdx.x * 256 + threadIdx.x; i < n4; i += gridDim.x * 256) {
    float4 v = ((const float4*)s)[i];
    union { unsigned short u[4]; uint2 p; } o;
    o.u[0] = f32_to_bf16(v.x); o.u[1] = f32_to_bf16(v.y);
    o.u[2] = f32_to_bf16(v.z); o.u[3] = f32_to_bf16(v.w);
    *(uint2*)&d[(long)i * 4] = o.p;
  }
}

// ---------------- ln0: x_in -> x (fp32) ----------------
__global__ __launch_bounds__(256) void ln0_kernel(const float* __restrict__ xin,
    const float* __restrict__ w, const float* __restrict__ b, float* __restrict__ xo){
  const int row = blockIdx.x, tid = threadIdx.x;
  const float* xr = xin + (long)row * CCH;
  float c4[4]; float s = 0.f, s2 = 0.f;
  #pragma unroll
  for (int j = 0; j < 4; j++){ c4[j] = xr[tid + j*256]; s += c4[j]; s2 += c4[j]*c4[j]; }
  s = wave_sum(s); s2 = wave_sum(s2);
  __shared__ float red[2][4];
  const int wid = tid >> 6, lane = tid & 63;
  if (lane == 0){ red[0][wid] = s; red[1][wid] = s2; }
  __syncthreads();
  const float S  = red[0][0]+red[0][1]+red[0][2]+red[0][3];
  const float S2 = red[1][0]+red[1][1]+red[1][2]+red[1][3];
  const float inv = 1.f / CCH;
  const float m = S * inv;
  const float rs = rsqrtf(S2 * inv - m*m + EPSV);
  float* xout = xo + (long)row * CCH;
  #pragma unroll
  for (int j = 0; j < 4; j++){ int c = tid + j*256; xout[c] = (c4[j]-m)*rs*w[c] + b[c]; }
}

// ---------------- fused LN + time-shift + mix -> bf16 ----------------
template<int NOUT>
__global__ __launch_bounds__(256) void ln_mix(
    const float* __restrict__ x,
    const float* __restrict__ lw, const float* __restrict__ lb,
    const float* __restrict__ mk, const float* __restrict__ mv, const float* __restrict__ mr,
    unsigned short* __restrict__ xk, unsigned short* __restrict__ xv, unsigned short* __restrict__ xr)
{
  const int row = blockIdx.x;
  const int t = row & (TT - 1);
  const int tid = threadIdx.x;
  const float* xc = x + (long)row * CCH;
  const float* xp = xc - CCH;
  float c4[4], p4[4];
  float s1=0.f, s2=0.f, s3=0.f, s4=0.f;
  #pragma unroll
  for (int j = 0; j < 4; j++){
    const int c = tid + j*256;
    c4[j] = xc[c];
    p4[j] = (t > 0) ? xp[c] : 0.f;
    s1 += c4[j]; s2 += c4[j]*c4[j];
    s3 += p4[j]; s4 += p4[j]*p4[j];
  }
  s1 = wave_sum(s1); s2 = wave_sum(s2); s3 = wave_sum(s3); s4 = wave_sum(s4);
  __shared__ float red[4][4];
  const int wid = tid >> 6, lane = tid & 63;
  if (lane == 0){ red[wid][0]=s1; red[wid][1]=s2; red[wid][2]=s3; red[wid][3]=s4; }
  __syncthreads();
  const float S1 = red[0][0]+red[1][0]+red[2][0]+red[3][0];
  const float S2 = red[0][1]+red[1][1]+red[2][1]+red[3][1];
  const float S3 = red[0][2]+red[1][2]+red[2][2]+red[3][2];
  const float S4 = red[0][3]+red[1][3]+red[2][3]+red[3][3];
  const float inv = 1.f / CCH;
  const float m1 = S1*inv; const float r1 = rsqrtf(S2*inv - m1*m1 + EPSV);
  const float m0 = S3*inv; const float r0 = rsqrtf(S4*inv - m0*m0 + EPSV);
  #pragma unroll
  for (int j = 0; j < 4; j++){
    const int c = tid + j*256;
    const long o = (long)row * CCH + c;
    const float wv = lw[c], bv = lb[c];
    const float h  = (c4[j]-m1)*r1*wv + bv;
    const float hp = (t > 0) ? ((p4[j]-m0)*r0*wv + bv) : 0.f;
    const float a = mk[c]; xk[o] = f32_to_bf16(h*a + hp*(1.f-a));
    if (NOUT == 3){ const float q = mv[c]; xv[o] = f32_to_bf16(h*q + hp*(1.f-q)); }
    const float g = mr[c]; xr[o] = f32_to_bf16(h*g + hp*(1.f-g));
  }
}

// ---------------- WKV blocked scan ----------------
__global__ __launch_bounds__(256) void wkv_pass1(
    const unsigned short* __restrict__ kin, const unsigned short* __restrict__ vin,
    const float* __restrict__ td,
    float* __restrict__ sta, float* __restrict__ stb, float* __restrict__ stp)
{
  const int c = blockIdx.x * 256 + threadIdx.x;
  const int chunk = blockIdx.y, b = blockIdx.z;
  const float w = -__expf(td[c]);
  const long base = ((long)b * TT + (long)chunk * CHKL) * CCH + c;
  float aa = 0.f, bb = 0.f, pp = -1e38f;
  for (int t0 = 0; t0 < CHKL; t0 += 8) {
    float kr[8], vr[8];
    #pragma unroll
    for (int j = 0; j < 8; j++){
      const long o = base + (long)(t0 + j) * CCH;
      kr[j] = bf16_to_f32(kin[o]);
      vr[j] = bf16_to_f32(vin[o]);
    }
    #pragma unroll
    for (int j = 0; j < 8; j++){
      const float kk = kr[j], vv = vr[j];
      const float ww2 = pp + w;
      const float qq2 = fmaxf(ww2, kk);
      const float e1b = __expf(ww2 - qq2), e2b = __expf(kk - qq2);
      aa = e1b*aa + e2b*vv; bb = e1b*bb + e2b; pp = qq2;
    }
  }
  const long si = (long)chunk * 4096 + b * CCH + c;
  sta[si] = aa; stb[si] = bb; stp[si] = pp;
}

__global__ __launch_bounds__(256) void wkv_combine(
    const float* __restrict__ td,
    const float* __restrict__ sta, const float* __restrict__ stb, const float* __restrict__ stp,
    float* __restrict__ ina, float* __restrict__ inb, float* __restrict__ inp)
{
  const int idx = blockIdx.x * 256 + threadIdx.x;   // b*C + c
  const int c = idx & (CCH - 1);
  const float wn = -__expf(td[c]) * (float)CHKL;
  float a = 0.f, b = 0.f, p = -1e38f;
  for (int j0 = 0; j0 < NCHK; j0 += 8) {
    float la[8], lb[8], lp[8];
    #pragma unroll
    for (int j = 0; j < 8; j++){
      const long si = (long)(j0 + j) * 4096 + idx;
      la[j] = sta[si]; lb[j] = stb[si]; lp[j] = stp[si];
    }
    #pragma unroll
    for (int j = 0; j < 8; j++){
      const long si = (long)(j0 + j) * 4096 + idx;
      ina[si] = a; inb[si] = b; inp[si] = p;
      const float pd = p + wn;
      const float q = fmaxf(pd, lp[j]);
      const float e1 = __expf(pd - q), e2 = __expf(lp[j] - q);
      a = e1*a + e2*la[j]; b = e1*b + e2*lb[j]; p = q;
    }
  }
}

__global__ __launch_bounds__(256) void wkv_pass2(
    const unsigned short* __restrict__ kin, const unsigned short* __restrict__ vin,
    const unsigned short* __restrict__ srin,
    const float* __restrict__ td, const float* __restrict__ tf,
    const float* __restrict__ ina, const float* __restrict__ inb, const float* __restrict__ inp,
    unsigned short* __restrict__ out)
{
  const int c = blockIdx.x * 256 + threadIdx.x;
  const int chunk = blockIdx.y, b = blockIdx.z;
  const float w = -__expf(td[c]);
  const float u = tf[c];
  const long si = (long)chunk * 4096 + b * CCH + c;
  float aa = ina[si], bb = inb[si], pp = inp[si];
  const long base = ((long)b * TT + (long)chunk * CHKL) * CCH + c;
  for (int t0 = 0; t0 < CHKL; t0 += 8) {
    float kr[8], vr[8], sr[8];
    #pragma unroll
    for (int j = 0; j < 8; j++){
      const long o = base + (long)(t0 + j) * CCH;
      kr[j] = bf16_to_f32(kin[o]);
      vr[j] = bf16_to_f32(vin[o]);
      sr[j] = bf16_to_f32(srin[o]);
    }
    #pragma unroll
    for (int j = 0; j < 8; j++){
      const float kk = kr[j], vv = vr[j];
      const float ww = u + kk;
      const float qq = fmaxf(pp, ww);
      const float e1 = __expf(pp - qq), e2 = __expf(ww - qq);
      const float outv = (e1*aa + e2*vv) / (e1*bb + e2);
      const float ww2 = pp + w;
      const float qq2 = fmaxf(ww2, kk);
      const float e1b = __expf(ww2 - qq2), e2b = __expf(kk - qq2);
      aa = e1b*aa + e2b*vv; bb = e1b*bb + e2b; pp = qq2;
      out[base + (long)(t0 + j) * CCH] = f32_to_bf16(sr[j] * outv);
    }
  }
}

// ---------------- bf16 MFMA GEMM: C[M,N] = A[M,K] * W[N,K]^T ----------------
// R10: R9's 3-slot BK=32 ring REGRESSED from bank conflicts (7.86M): 64B
// rows only span half a 32-bank line. Fix: PAIR-PACKED 128B lines — two
// consecutive rows per line, logical (row, chunk c in 0..3) stored at
//   line = row>>1, 16B-slot p = (c | ((row&1)<<2)) ^ (line&7)
// Every line = full 128B over all 8 bank groups, XOR key cycles 0..7:
// structurally the R4/R8-proven conflict-free pattern. Frag read group
// p = (quad|((r16&1)<<2)) ^ (r16>>1) is a bijection (quad,parity)<->group
// per key => exactly 8 lanes/bank-group, distinct addrs (= R8 balance).
// Also dropped the redundant lgkmcnt(0) (MFMA data-dep already forces each
// wave's reads complete pre-barrier). Schedule (race-proof as R9):
//   iter t: stage(t+2 -> slot (t+2)%3) | ds_read slot t%3 | MFMA |
//           vmcnt(LPT) | barrier        (never drains mid-loop)
#define BK 32

enum { EP_BF16 = 0, EP_ADD = 3, EP_MULADD = 4, EP_KVR = 5, EP_FFN1 = 6 };

template<int EPI, int BMt>
__global__ __launch_bounds__(256, (BMt == 128) ? 3 : 2) void gemm_bt(
    const unsigned short* __restrict__ A,
    const unsigned short* __restrict__ W,
    int N, const int K,
    unsigned short* __restrict__ outb,
    float* __restrict__ xres,
    const unsigned short* __restrict__ rr,
    const unsigned short* __restrict__ A2,
    const unsigned short* __restrict__ W2,
    unsigned short* __restrict__ outb2,
    const int N2)
{
  constexpr int MR = BMt / 2 / 16;       // 8 (BMt=256) or 4 (BMt=128)
  constexpr int NR = 4;                  // BN=128, 2 col-waves
  constexpr int LA = BMt / 64;           // A 16B-positions per thread: 4 or 2
  constexpr int LB = 2;                  // B 16B-positions per thread
  constexpr int LPT = LA + LB;           // 6 or 4

  const int bm = blockIdx.x;
  int bn = blockIdx.y;
  bool sig = false;
  if (EPI == EP_KVR) {
    const long z = blockIdx.z;
    const long Mfull = (long)gridDim.x * BMt;
    A    += z * Mfull * K;
    W    += z * (long)N * K;
    outb += z * Mfull * N;
    sig = (blockIdx.z == 2);
  }
  if (EPI == EP_FFN1) {
    if (blockIdx.z == 1) {
      if (bn >= N2 / 128) return;   // block-uniform early-exit, before any barrier
      A = A2; W = W2; outb = outb2; N = N2; sig = true;
    }
  }
  __shared__ unsigned short lA[3][BMt * BK];   // 3 x 16/8 KB
  __shared__ unsigned short lW[3][128 * BK];   // 3 x 8 KB
  const int tid = threadIdx.x;
  const int wid = tid >> 6, lane = tid & 63;
  const int wm = (wid >> 1), wn = (wid & 1);
  const int quad = lane >> 4, r16 = lane & 15;
  const int WR = wm * (MR * 16);

  // staging: thread covers 16B-position P = i*256 + tid within the slot.
  //   line = P>>3, p = P&7, pu = p ^ (line&7) -> row = 2*line + (pu>>2),
  //   chunk c = pu&3. Pre-swizzled GLOBAL source, linear LDS dest (rule #21).
  const unsigned short* aSrc[LA]; int aDst[LA];
  #pragma unroll
  for (int i = 0; i < LA; i++) {
    const int P = i * 256 + tid;
    const int line = P >> 3;
    const int pu = (P & 7) ^ (line & 7);
    const int row = 2 * line + (pu >> 2);
    const int c = pu & 3;
    aSrc[i] = A + (long)(bm * BMt + row) * K + c * 8;
    aDst[i] = P * 8;
  }
  const unsigned short* bSrc[LB]; int bDst[LB];
  #pragma unroll
  for (int i = 0; i < LB; i++) {
    const int P = i * 256 + tid;
    const int line = P >> 3;
    const int pu = (P & 7) ^ (line & 7);
    const int row = 2 * line + (pu >> 2);
    const int c = pu & 3;
    bSrc[i] = W + (long)(bn * 128 + row) * K + c * 8;
    bDst[i] = P * 8;
  }

  // fragment reads: for row R = base16 + r16, chunk quad:
  //   addr(shorts) = (R>>1)*64 + ((quad | ((R&1)<<2)) ^ ((R>>1)&7))*8
  // base16 multiple of 16 => key = r16>>1, parity = r16&1 (per-thread const).
  const int pswz = (quad | ((r16 & 1) << 2)) ^ (r16 >> 1);
  const int aoff = (WR / 2 + (r16 >> 1)) * 64 + pswz * 8;
  const int boff = (wn * 32 + (r16 >> 1)) * 64 + pswz * 8;

  const floatx4 zf = {0.f, 0.f, 0.f, 0.f};
  floatx4 acc[MR][NR];
  #pragma unroll
  for (int i = 0; i < MR; i++)
    #pragma unroll
    for (int j = 0; j < NR; j++) acc[i][j] = zf;

  const int NT = K / BK;

  // prologue: tiles 0,1 into slots 0,1; wait tile 0 (LPT of tile 1 in flight)
  #pragma unroll
  for (int tt = 0; tt < 2; ++tt) {
    const long ko = (long)tt * BK;
    #pragma unroll
    for (int i = 0; i < LA; i++) async16(aSrc[i] + ko, &lA[tt][aDst[i]]);
    #pragma unroll
    for (int i = 0; i < LB; i++) async16(bSrc[i] + ko, &lW[tt][bDst[i]]);
  }
  asm volatile("s_waitcnt vmcnt(%0)" :: "n"(LPT) : "memory");
  __builtin_amdgcn_s_barrier();
  __builtin_amdgcn_sched_barrier(0);

  int s = 0, s2 = 2;   // slot of tile t, slot of tile t+2
  for (int t = 0; t < NT; ++t) {
    // stage tile t+2 into slot s2 (slot of tile t-1: all waves' reads of it
    // completed before the end-of-(t-1) barrier via MFMA data-deps)
    if (t + 2 < NT) {
      const long ko = (long)(t + 2) * BK;
      #pragma unroll
      for (int i = 0; i < LA; i++) async16(aSrc[i] + ko, &lA[s2][aDst[i]]);
      #pragma unroll
      for (int i = 0; i < LB; i++) async16(bSrc[i] + ko, &lW[s2][bDst[i]]);
    }
    // fragments for tile t from slot s
    shortx8 af[MR], bf[NR];
    #pragma unroll
    for (int m = 0; m < MR; m++)
      af[m] = *(const shortx8*)&lA[s][aoff + m * 512];
    #pragma unroll
    for (int n = 0; n < NR; n++)
      bf[n] = *(const shortx8*)&lW[s][boff + n * 512];
    __builtin_amdgcn_s_setprio(1);
    #pragma unroll
    for (int m = 0; m < MR; m++)
      #pragma unroll
      for (int n = 0; n < NR; n++)
        acc[m][n] = __builtin_amdgcn_mfma_f32_16x16x32_bf16(af[m], bf[n], acc[m][n], 0, 0, 0);
    __builtin_amdgcn_s_setprio(0);
    __builtin_amdgcn_sched_barrier(0);
    // counted wait: tile t+1 resident for all waves after the barrier;
    // tile t+2 stays in flight (never drains mid-loop). Tail: LPT -> 0.
    if (t + 2 < NT)      asm volatile("s_waitcnt vmcnt(%0)" :: "n"(LPT) : "memory");
    else if (t + 1 < NT) asm volatile("s_waitcnt vmcnt(0)" ::: "memory");
    if (t + 1 < NT) {
      __builtin_amdgcn_s_barrier();
      __builtin_amdgcn_sched_barrier(0);
    }
    s = (s == 2) ? 0 : s + 1;
    s2 = (s2 == 2) ? 0 : s2 + 1;
  }

  const int colBase = bn * 128 + wn * 64 + r16;
  #pragma unroll
  for (int m = 0; m < MR; m++) {
    const int rowBase = bm * BMt + WR + m * 16 + quad * 4;
    #pragma unroll
    for (int n = 0; n < NR; n++) {
      const int col = colBase + n * 16;
      #pragma unroll
      for (int r = 0; r < 4; r++) {
        const long idx = (long)(rowBase + r) * N + col;
        const float val = acc[m][n][r];
        if (EPI == EP_KVR)       outb[idx] = sig ? f32_to_bf16(1.f / (1.f + __expf(-val)))
                                                 : f32_to_bf16(val);
        else if (EPI == EP_FFN1) {
          if (sig) outb[idx] = f32_to_bf16(1.f / (1.f + __expf(-val)));
          else     { const float t = val > 0.f ? val : 0.f; outb[idx] = f32_to_bf16(t * t); }
        }
        else if (EPI == EP_ADD)  xres[idx] += val;
        else if (EPI == EP_MULADD) xres[idx] = fmaf(bf16_to_f32(rr[idx]), val, xres[idx]);
        else                     outb[idx] = f32_to_bf16(val);
      }
    }
  }
}

extern "C" void kernel_launch(void* const* d_in, const int* in_sizes, int n_in,
                              void* d_out, int out_size, void* d_ws, size_t ws_size,
                              hipStream_t stream)
{
  const float* x_in       = (const float*)d_in[0];
  const float* ln0_w      = (const float*)d_in[1];
  const float* ln0_b      = (const float*)d_in[2];
  const float* ln1_w      = (const float*)d_in[3];
  const float* ln1_b      = (const float*)d_in[4];
  const float* ln2_w      = (const float*)d_in[5];
  const float* ln2_b      = (const float*)d_in[6];
  const float* time_decay = (const float*)d_in[7];
  const float* time_first = (const float*)d_in[8];
  const float* tmk        = (const float*)d_in[9];
  const float* tmv        = (const float*)d_in[10];
  const float* tmr        = (const float*)d_in[11];
  const float* Wk         = (const float*)d_in[12];
  const float* Wv         = (const float*)d_in[13];
  const float* Wr         = (const float*)d_in[14];
  const float* Wo         = (const float*)d_in[15];
  const float* cmk        = (const float*)d_in[16];
  const float* cmr        = (const float*)d_in[17];
  const float* Wck        = (const float*)d_in[18];
  const float* Wcv        = (const float*)d_in[19];
  const float* Wcr        = (const float*)d_in[20];
  float* x = (float*)d_out;

  const int M = 4 * TT;                 // 8192 rows
  const long lCC = (long)CCH * CCH;
  const long lFC = (long)FFD * CCH;
  const long MC  = (long)M * CCH;

  unsigned short* wsl  = (unsigned short*)d_ws;
  unsigned short* wkb  = wsl;
  unsigned short* wvb  = wkb + lCC;
  unsigned short* wrb  = wvb + lCC;
  unsigned short* wob  = wrb + lCC;
  unsigned short* wcrb = wob + lCC;
  unsigned short* wckb = wcrb + lCC;
  unsigned short* wcvb = wckb + lFC;
  unsigned short* xk   = wcvb + lFC;
  unsigned short* xv   = xk + MC;
  unsigned short* xr   = xv + MC;
  unsigned short* kbuf = xr + MC;       // region reused as kf [M,F]
  unsigned short* vbuf = kbuf + MC;
  unsigned short* sbuf = vbuf + MC;
  unsigned short* kfb  = kbuf;
  unsigned short* rrb  = kbuf + (long)M * FFD;

  // WKV scan state in the (dead between GEMMs) xk region
  float* sta = (float*)xk;
  float* stb = sta + (long)NCHK * 4096;
  float* stp = stb + (long)NCHK * 4096;
  float* ina = stp + (long)NCHK * 4096;
  float* inb = ina + (long)NCHK * 4096;
  float* inp = inb + (long)NCHK * 4096;

  ln0_kernel<<<M, 256, 0, stream>>>(x_in, ln0_w, ln0_b, x);

  const dim3 gkvr(M / 256, CCH / 128, 3);  // (32, 8, 3)  = 768 blocks, BMt=256
  const dim3 g1  (M / 128, CCH / 128);     // (64, 8)     = 512 blocks, BMt=128
  const dim3 gffn(M / 256, FFD / 128, 2);  // (32, 32, 2), BMt=256; z1 = r sigmoid (bn<8)
  const dim3 gw(CCH / 256, NCHK, 4);       // (4, 32, 4)

  for (int l = 0; l < 4; l++) {
    CvtArgs ca;
    ca.s[0] = Wk  + (long)l * lCC; ca.d[0] = wkb;  ca.n4[0] = (int)(lCC / 4);
    ca.s[1] = Wv  + (long)l * lCC; ca.d[1] = wvb;  ca.n4[1] = (int)(lCC / 4);
    ca.s[2] = Wr  + (long)l * lCC; ca.d[2] = wrb;  ca.n4[2] = (int)(lCC / 4);
    ca.s[3] = Wo  + (long)l * lCC; ca.d[3] = wob;  ca.n4[3] = (int)(lCC / 4);
    ca.s[4] = Wcr + (long)l * lCC; ca.d[4] = wcrb; ca.n4[4] = (int)(lCC / 4);
    ca.s[5] = Wck + (long)l * lFC; ca.d[5] = wckb; ca.n4[5] = (int)(lFC / 4);
    ca.s[6] = Wcv + (long)l * lFC; ca.d[6] = wcvb; ca.n4[6] = (int)(lFC / 4);
    cvt7_kernel<<<dim3(512, 7), 256, 0, stream>>>(ca);

    const float* td_l = time_decay + l*CCH;
    const float* tf_l = time_first + l*CCH;

    // --- TimeMix ---
    ln_mix<3><<<M, 256, 0, stream>>>(x, ln1_w + l*CCH, ln1_b + l*CCH,
                                     tmk + l*CCH, tmv + l*CCH, tmr + l*CCH, xk, xv, xr);
    gemm_bt<EP_KVR, 256><<<gkvr, 256, 0, stream>>>(xk, wkb, CCH, CCH, kbuf, nullptr,
                                              nullptr, nullptr, nullptr, nullptr, 0);
    wkv_pass1 <<<gw, 256, 0, stream>>>(kbuf, vbuf, td_l, sta, stb, stp);
    wkv_combine<<<16, 256, 0, stream>>>(td_l, sta, stb, stp, ina, inb, inp);
    wkv_pass2 <<<gw, 256, 0, stream>>>(kbuf, vbuf, sbuf, td_l, tf_l, ina, inb, inp, xv);
    gemm_bt<EP_ADD, 128><<<g1, 256, 0, stream>>>(xv, wob, CCH, CCH, nullptr, x, nullptr,
                                             nullptr, nullptr, nullptr, 0);

    // --- ChannelMix ---
    ln_mix<2><<<M, 256, 0, stream>>>(x, ln2_w + l*CCH, ln2_b + l*CCH,
                                     cmk + l*CCH, nullptr, cmr + l*CCH, xk, nullptr, xr);
    gemm_bt<EP_FFN1, 256><<<gffn, 256, 0, stream>>>(xk, wckb, FFD, CCH, kfb, nullptr,
                                               nullptr, xr, wcrb, rrb, CCH);
    gemm_bt<EP_MULADD, 128><<<g1, 256, 0, stream>>>(kfb, wcvb, CCH, FFD, nullptr, x, rrb,
                                               nullptr, nullptr, nullptr, 0);
  }
}

// Round 6
// 1610.935 us; speedup vs baseline: 1.1936x; 1.1733x over previous
//
#include <hip/hip_runtime.h>
#include <cstdint>

#define TT 2048
#define CCH 1024
#define FFD 4096
#define EPSV 1e-5f
#define NCHK 32
#define CHKL 64   // TT / NCHK

typedef __attribute__((ext_vector_type(4))) float floatx4;
typedef __attribute__((ext_vector_type(8))) short shortx8;

__device__ __forceinline__ unsigned short f32_to_bf16(float f){
  union { float f; unsigned int u; } x; x.f = f;
  unsigned int r = x.u + 0x7fffu + ((x.u >> 16) & 1u);
  return (unsigned short)(r >> 16);
}
__device__ __forceinline__ float bf16_to_f32(unsigned short h){
  union { unsigned int u; float f; } x; x.u = ((unsigned int)h) << 16;
  return x.f;
}
__device__ __forceinline__ float wave_sum(float v){
  #pragma unroll
  for (int o = 32; o > 0; o >>= 1) v += __shfl_down(v, o, 64);
  return v;
}
__device__ __forceinline__ void async16(const void* g, void* l){
  __builtin_amdgcn_global_load_lds((const __attribute__((address_space(1))) void*)g,
                                   (__attribute__((address_space(3))) void*)l, 16, 0, 0);
}

// ---------------- fp32 -> bf16 weight conversion (7 segments) ----------------
struct CvtArgs {
  const float* s[7];
  unsigned short* d[7];
  int n4[7];
};
__device__ __forceinline__ void cvt_body(const CvtArgs& a, int seg){
  const float* __restrict__ s = a.s[seg];
  unsigned short* __restrict__ d = a.d[seg];
  const int n4 = a.n4[seg];
  for (int i = blockIdx.x * 256 + threadIdx.x; i < n4; i += gridDim.x * 256) {
    float4 v = ((const float4*)s)[i];
    union { unsigned short u[4]; uint2 p; } o;
    o.u[0] = f32_to_bf16(v.x); o.u[1] = f32_to_bf16(v.y);
    o.u[2] = f32_to_bf16(v.z); o.u[3] = f32_to_bf16(v.w);
    *(uint2*)&d[(long)i * 4] = o.p;
  }
}

// ---------------- ln0: x_in -> x (fp32) ----------------
__global__ __launch_bounds__(256) void ln0_kernel(const float* __restrict__ xin,
    const float* __restrict__ w, const float* __restrict__ b, float* __restrict__ xo){
  const int row = blockIdx.x, tid = threadIdx.x;
  const float* xr = xin + (long)row * CCH;
  float c4[4]; float s = 0.f, s2 = 0.f;
  #pragma unroll
  for (int j = 0; j < 4; j++){ c4[j] = xr[tid + j*256]; s += c4[j]; s2 += c4[j]*c4[j]; }
  s = wave_sum(s); s2 = wave_sum(s2);
  __shared__ float red[2][4];
  const int wid = tid >> 6, lane = tid & 63;
  if (lane == 0){ red[0][wid] = s; red[1][wid] = s2; }
  __syncthreads();
  const float S  = red[0][0]+red[0][1]+red[0][2]+red[0][3];
  const float S2 = red[1][0]+red[1][1]+red[1][2]+red[1][3];
  const float inv = 1.f / CCH;
  const float m = S * inv;
  const float rs = rsqrtf(S2 * inv - m*m + EPSV);
  float* xout = xo + (long)row * CCH;
  #pragma unroll
  for (int j = 0; j < 4; j++){ int c = tid + j*256; xout[c] = (c4[j]-m)*rs*w[c] + b[c]; }
}

// ---------------- fused LN + time-shift + mix -> bf16 (body) ----------------
template<int NOUT>
__device__ __forceinline__ void lnmix_body(
    const float* __restrict__ x,
    const float* __restrict__ lw, const float* __restrict__ lb,
    const float* __restrict__ mk, const float* __restrict__ mv, const float* __restrict__ mr,
    unsigned short* __restrict__ xk, unsigned short* __restrict__ xv, unsigned short* __restrict__ xr)
{
  const int row = blockIdx.x;
  const int t = row & (TT - 1);
  const int tid = threadIdx.x;
  const float* xc = x + (long)row * CCH;
  const float* xp = xc - CCH;
  float c4[4], p4[4];
  float s1=0.f, s2=0.f, s3=0.f, s4=0.f;
  #pragma unroll
  for (int j = 0; j < 4; j++){
    const int c = tid + j*256;
    c4[j] = xc[c];
    p4[j] = (t > 0) ? xp[c] : 0.f;
    s1 += c4[j]; s2 += c4[j]*c4[j];
    s3 += p4[j]; s4 += p4[j]*p4[j];
  }
  s1 = wave_sum(s1); s2 = wave_sum(s2); s3 = wave_sum(s3); s4 = wave_sum(s4);
  __shared__ float red[4][4];
  const int wid = tid >> 6, lane = tid & 63;
  if (lane == 0){ red[wid][0]=s1; red[wid][1]=s2; red[wid][2]=s3; red[wid][3]=s4; }
  __syncthreads();
  const float S1 = red[0][0]+red[1][0]+red[2][0]+red[3][0];
  const float S2 = red[0][1]+red[1][1]+red[2][1]+red[3][1];
  const float S3 = red[0][2]+red[1][2]+red[2][2]+red[3][2];
  const float S4 = red[0][3]+red[1][3]+red[2][3]+red[3][3];
  const float inv = 1.f / CCH;
  const float m1 = S1*inv; const float r1 = rsqrtf(S2*inv - m1*m1 + EPSV);
  const float m0 = S3*inv; const float r0 = rsqrtf(S4*inv - m0*m0 + EPSV);
  #pragma unroll
  for (int j = 0; j < 4; j++){
    const int c = tid + j*256;
    const long o = (long)row * CCH + c;
    const float wv = lw[c], bv = lb[c];
    const float h  = (c4[j]-m1)*r1*wv + bv;
    const float hp = (t > 0) ? ((p4[j]-m0)*r0*wv + bv) : 0.f;
    const float a = mk[c]; xk[o] = f32_to_bf16(h*a + hp*(1.f-a));
    if (NOUT == 3){ const float q = mv[c]; xv[o] = f32_to_bf16(h*q + hp*(1.f-q)); }
    const float g = mr[c]; xr[o] = f32_to_bf16(h*g + hp*(1.f-g));
  }
}

template<int NOUT>
__global__ __launch_bounds__(256) void ln_mix(
    const float* __restrict__ x,
    const float* __restrict__ lw, const float* __restrict__ lb,
    const float* __restrict__ mk, const float* __restrict__ mv, const float* __restrict__ mr,
    unsigned short* __restrict__ xk, unsigned short* __restrict__ xv, unsigned short* __restrict__ xr)
{
  lnmix_body<NOUT>(x, lw, lb, mk, mv, mr, xk, xv, xr);
}

// fused: y==0 -> ln_mix<3> row = blockIdx.x; y>=1 -> cvt segment y-1
__global__ __launch_bounds__(256) void lnmix3_cvt(CvtArgs a,
    const float* __restrict__ x,
    const float* __restrict__ lw, const float* __restrict__ lb,
    const float* __restrict__ mk, const float* __restrict__ mv, const float* __restrict__ mr,
    unsigned short* __restrict__ xk, unsigned short* __restrict__ xv, unsigned short* __restrict__ xr)
{
  if (blockIdx.y == 0) {
    lnmix_body<3>(x, lw, lb, mk, mv, mr, xk, xv, xr);
  } else {
    cvt_body(a, blockIdx.y - 1);
  }
}

// ---------------- WKV blocked scan ----------------
__global__ __launch_bounds__(256) void wkv_pass1(
    const unsigned short* __restrict__ kin, const unsigned short* __restrict__ vin,
    const float* __restrict__ td,
    float* __restrict__ sta, float* __restrict__ stb, float* __restrict__ stp)
{
  const int c = blockIdx.x * 256 + threadIdx.x;
  const int chunk = blockIdx.y, b = blockIdx.z;
  const float w = -__expf(td[c]);
  const long base = ((long)b * TT + (long)chunk * CHKL) * CCH + c;
  float aa = 0.f, bb = 0.f, pp = -1e38f;
  for (int t0 = 0; t0 < CHKL; t0 += 8) {
    float kr[8], vr[8];
    #pragma unroll
    for (int j = 0; j < 8; j++){
      const long o = base + (long)(t0 + j) * CCH;
      kr[j] = bf16_to_f32(kin[o]);
      vr[j] = bf16_to_f32(vin[o]);
    }
    #pragma unroll
    for (int j = 0; j < 8; j++){
      const float kk = kr[j], vv = vr[j];
      const float ww2 = pp + w;
      const float qq2 = fmaxf(ww2, kk);
      const float e1b = __expf(ww2 - qq2), e2b = __expf(kk - qq2);
      aa = e1b*aa + e2b*vv; bb = e1b*bb + e2b; pp = qq2;
    }
  }
  const long si = (long)chunk * 4096 + b * CCH + c;
  sta[si] = aa; stb[si] = bb; stp[si] = pp;
}

// pass2 with INLINED chunk-prefix combine (removes the wkv_combine dispatch
// and the ina/inb/inp round-trip): each block reconstructs the state
// entering its chunk from sta/stb/stp (<=31 cheap iterations).
__global__ __launch_bounds__(256) void wkv_pass2(
    const unsigned short* __restrict__ kin, const unsigned short* __restrict__ vin,
    const unsigned short* __restrict__ srin,
    const float* __restrict__ td, const float* __restrict__ tf,
    const float* __restrict__ sta, const float* __restrict__ stb, const float* __restrict__ stp,
    unsigned short* __restrict__ out)
{
  const int c = blockIdx.x * 256 + threadIdx.x;
  const int chunk = blockIdx.y, b = blockIdx.z;
  const float w = -__expf(td[c]);
  const float u = tf[c];
  const float wn = w * (float)CHKL;
  float aa = 0.f, bb = 0.f, pp = -1e38f;
  for (int j = 0; j < chunk; ++j) {
    const long sj = (long)j * 4096 + b * CCH + c;
    const float la = sta[sj], lb = stb[sj], lp = stp[sj];
    const float pd = pp + wn;
    const float q = fmaxf(pd, lp);
    const float e1 = __expf(pd - q), e2 = __expf(lp - q);
    aa = e1*aa + e2*la; bb = e1*bb + e2*lb; pp = q;
  }
  const long base = ((long)b * TT + (long)chunk * CHKL) * CCH + c;
  for (int t0 = 0; t0 < CHKL; t0 += 8) {
    float kr[8], vr[8], sr[8];
    #pragma unroll
    for (int j = 0; j < 8; j++){
      const long o = base + (long)(t0 + j) * CCH;
      kr[j] = bf16_to_f32(kin[o]);
      vr[j] = bf16_to_f32(vin[o]);
      sr[j] = bf16_to_f32(srin[o]);
    }
    #pragma unroll
    for (int j = 0; j < 8; j++){
      const float kk = kr[j], vv = vr[j];
      const float ww = u + kk;
      const float qq = fmaxf(pp, ww);
      const float e1 = __expf(pp - qq), e2 = __expf(ww - qq);
      const float outv = (e1*aa + e2*vv) / (e1*bb + e2);
      const float ww2 = pp + w;
      const float qq2 = fmaxf(ww2, kk);
      const float e1b = __expf(ww2 - qq2), e2b = __expf(kk - qq2);
      aa = e1b*aa + e2b*vv; bb = e1b*bb + e2b; pp = qq2;
      out[base + (long)(t0 + j) * CCH] = f32_to_bf16(sr[j] * outv);
    }
  }
}

// ---------------- bf16 MFMA GEMM: C[M,N] = A[M,K] * W[N,K]^T ----------------
// R11: KVR/FFN1 keep the R8-verified structure exactly (BMt=256, BK=64,
// 2-barrier loop, XOR chunk swizzle, 2 blocks/CU implicit overlap; FFN1
// measured 942 TF = this structure's ceiling). The BK=32 ring experiments
// (R9/R10) lost to it even at 0 bank conflicts -> abandoned.
#define BK 64

enum { EP_BF16 = 0, EP_ADD = 3, EP_MULADD = 4, EP_KVR = 5, EP_FFN1 = 6 };

template<int EPI, int BMt>
__global__ __launch_bounds__(256, 3) void gemm_bt(
    const unsigned short* __restrict__ A,
    const unsigned short* __restrict__ W,
    int N, const int K,
    unsigned short* __restrict__ outb,
    float* __restrict__ xres,
    const unsigned short* __restrict__ rr,
    const unsigned short* __restrict__ A2,
    const unsigned short* __restrict__ W2,
    unsigned short* __restrict__ outb2,
    const int N2)
{
  constexpr int MR = BMt / 2 / 16;   // 8 (BMt=256)
  constexpr int NR = 4;              // BN=128, 2 col-waves

  const int bm = blockIdx.x;
  int bn = blockIdx.y;
  bool sig = false;
  if (EPI == EP_KVR) {
    const long z = blockIdx.z;
    const long Mfull = (long)gridDim.x * BMt;
    A    += z * Mfull * K;
    W    += z * (long)N * K;
    outb += z * Mfull * N;
    sig = (blockIdx.z == 2);
  }
  if (EPI == EP_FFN1) {
    if (blockIdx.z == 1) {
      if (bn >= N2 / 128) return;   // block-uniform early-exit, before any barrier
      A = A2; W = W2; outb = outb2; N = N2; sig = true;
    }
  }
  __shared__ unsigned short lA[BMt * BK];   // 32 KB
  __shared__ unsigned short lW[128 * BK];   // 16 KB
  const int tid = threadIdx.x;
  const int wid = tid >> 6, lane = tid & 63;
  const int wm = (wid >> 1), wn = (wid & 1);
  const int quad = lane >> 4, r16 = lane & 15;

  const int srow = tid >> 3;
  const int scol = (tid & 7) ^ (srow & 7);
  const unsigned short* Ag = A + ((long)(bm * BMt + srow)) * K + scol * 8;
  const unsigned short* Wg = W + ((long)(bn * 128 + srow)) * K + scol * 8;
  const long rs32 = (long)32 * K;

  const int sw0 = ((quad)     ^ (r16 & 7)) * 8;
  const int sw1 = ((4 + quad) ^ (r16 & 7)) * 8;

  const floatx4 zf = {0.f, 0.f, 0.f, 0.f};
  floatx4 acc[MR][NR];
  #pragma unroll
  for (int i = 0; i < MR; i++)
    #pragma unroll
    for (int j = 0; j < NR; j++) acc[i][j] = zf;

  for (int k0 = 0; k0 < K; k0 += BK) {
    __syncthreads();
    #pragma unroll
    for (int i = 0; i < 4; i++) {
      if (BMt == 256) {
        async16(Ag + (long)(2*i)   * rs32 + k0, &lA[((2*i)   * 256 + tid) * 8]);
        async16(Ag + (long)(2*i+1) * rs32 + k0, &lA[((2*i+1) * 256 + tid) * 8]);
      } else {
        async16(Ag + (long)i * rs32 + k0, &lA[(i * 256 + tid) * 8]);
      }
      async16(Wg + (long)i * rs32 + k0, &lW[(i * 256 + tid) * 8]);
    }
    __syncthreads();
    #pragma unroll
    for (int kk = 0; kk < 2; kk++) {
      const int sw = kk ? sw1 : sw0;
      shortx8 af[MR], bf[NR];
      #pragma unroll
      for (int m = 0; m < MR; m++)
        af[m] = *(const shortx8*)&lA[(wm * (MR*16) + m*16 + r16) * 64 + sw];
      #pragma unroll
      for (int n = 0; n < NR; n++)
        bf[n] = *(const shortx8*)&lW[(wn * 64 + n*16 + r16) * 64 + sw];
      #pragma unroll
      for (int m = 0; m < MR; m++)
        #pragma unroll
        for (int n = 0; n < NR; n++)
          acc[m][n] = __builtin_amdgcn_mfma_f32_16x16x32_bf16(af[m], bf[n], acc[m][n], 0, 0, 0);
    }
  }

  const int colBase = bn * 128 + wn * 64 + r16;
  #pragma unroll
  for (int m = 0; m < MR; m++) {
    const int rowBase = bm * BMt + wm * (MR*16) + m * 16 + quad * 4;
    #pragma unroll
    for (int n = 0; n < NR; n++) {
      const int col = colBase + n * 16;
      #pragma unroll
      for (int r = 0; r < 4; r++) {
        const long idx = (long)(rowBase + r) * N + col;
        const float val = acc[m][n][r];
        if (EPI == EP_KVR)       outb[idx] = sig ? f32_to_bf16(1.f / (1.f + __expf(-val)))
                                                 : f32_to_bf16(val);
        else if (EPI == EP_FFN1) {
          if (sig) outb[idx] = f32_to_bf16(1.f / (1.f + __expf(-val)));
          else     { const float t = val > 0.f ? val : 0.f; outb[idx] = f32_to_bf16(t * t); }
        }
        else if (EPI == EP_ADD)  xres[idx] += val;
        else if (EPI == EP_MULADD) xres[idx] = fmaf(bf16_to_f32(rr[idx]), val, xres[idx]);
        else                     outb[idx] = f32_to_bf16(val);
      }
    }
  }
}

// R11 NEW: T3-minimum 2-phase double-buffer GEMM for the N=1024 GEMMs
// (ADD, MULADD; BMt=128, BK=64, 2x32KB LDS -> still 2 blocks/CU).
// Per tile t: STAGE(buf^1, t+1) FIRST, then ds_read+MFMA from buf, then ONE
// vmcnt(0)+s_barrier. Load latency flies under the tile's own MFMA block
// instead of being drained right after issue (the R8 2-barrier stall).
// Race proof: every wave's buf-reads complete before its MFMAs issue
// (in-order), hence before it reaches the barrier; vmcnt(0)+barrier then
// guarantees buf^1 fully landed for all waves before the next tile reads it.
template<int EPI>
__global__ __launch_bounds__(256, 2) void gemm2p(
    const unsigned short* __restrict__ A,
    const unsigned short* __restrict__ W,
    const int N, const int K,
    float* __restrict__ xres,
    const unsigned short* __restrict__ rr)
{
  __shared__ unsigned short lA[2][128 * BK];   // 2 x 16 KB
  __shared__ unsigned short lW[2][128 * BK];   // 2 x 16 KB
  const int bm = blockIdx.x, bn = blockIdx.y;
  const int tid = threadIdx.x;
  const int wid = tid >> 6, lane = tid & 63;
  const int wm = (wid >> 1), wn = (wid & 1);
  const int quad = lane >> 4, r16 = lane & 15;

  const int srow = tid >> 3;
  const int scol = (tid & 7) ^ (srow & 7);
  const unsigned short* Ag = A + ((long)(bm * 128 + srow)) * K + scol * 8;
  const unsigned short* Wg = W + ((long)(bn * 128 + srow)) * K + scol * 8;
  const long rs32 = (long)32 * K;

  const int sw0 = ((quad)     ^ (r16 & 7)) * 8;
  const int sw1 = ((4 + quad) ^ (r16 & 7)) * 8;

  const floatx4 zf = {0.f, 0.f, 0.f, 0.f};
  floatx4 acc[4][4];
  #pragma unroll
  for (int i = 0; i < 4; i++)
    #pragma unroll
    for (int j = 0; j < 4; j++) acc[i][j] = zf;

  const int NT = K / BK;

  // prologue: tile 0 -> buf 0
  #pragma unroll
  for (int i = 0; i < 4; i++) {
    async16(Ag + (long)i * rs32, &lA[0][(i * 256 + tid) * 8]);
    async16(Wg + (long)i * rs32, &lW[0][(i * 256 + tid) * 8]);
  }
  asm volatile("s_waitcnt vmcnt(0)" ::: "memory");
  __builtin_amdgcn_s_barrier();
  __builtin_amdgcn_sched_barrier(0);

  int cur = 0;
  for (int t = 0; t < NT; ++t) {
    // phase A: issue next-tile staging FIRST (into the other buffer)
    if (t + 1 < NT) {
      const long k0 = (long)(t + 1) * BK;
      const int nb = cur ^ 1;
      #pragma unroll
      for (int i = 0; i < 4; i++) {
        async16(Ag + (long)i * rs32 + k0, &lA[nb][(i * 256 + tid) * 8]);
        async16(Wg + (long)i * rs32 + k0, &lW[nb][(i * 256 + tid) * 8]);
      }
    }
    __builtin_amdgcn_sched_barrier(0);
    // phase B: ds_read + MFMA from current buffer
    #pragma unroll
    for (int kk = 0; kk < 2; kk++) {
      const int sw = kk ? sw1 : sw0;
      shortx8 af[4], bf[4];
      #pragma unroll
      for (int m = 0; m < 4; m++) af[m] = *(const shortx8*)&lA[cur][(wm * 64 + m*16 + r16) * 64 + sw];
      #pragma unroll
      for (int n = 0; n < 4; n++) bf[n] = *(const shortx8*)&lW[cur][(wn * 64 + n*16 + r16) * 64 + sw];
      __builtin_amdgcn_s_setprio(1);
      #pragma unroll
      for (int m = 0; m < 4; m++)
        #pragma unroll
        for (int n = 0; n < 4; n++)
          acc[m][n] = __builtin_amdgcn_mfma_f32_16x16x32_bf16(af[m], bf[n], acc[m][n], 0, 0, 0);
      __builtin_amdgcn_s_setprio(0);
    }
    // single per-tile sync: drain next-tile loads (they flew under the MFMAs)
    if (t + 1 < NT) {
      asm volatile("s_waitcnt vmcnt(0)" ::: "memory");
      __builtin_amdgcn_s_barrier();
      __builtin_amdgcn_sched_barrier(0);
      cur ^= 1;
    }
  }

  const int colBase = bn * 128 + wn * 64 + r16;
  #pragma unroll
  for (int m = 0; m < 4; m++) {
    const int rowBase = bm * 128 + wm * 64 + m * 16 + quad * 4;
    #pragma unroll
    for (int n = 0; n < 4; n++) {
      const int col = colBase + n * 16;
      #pragma unroll
      for (int r = 0; r < 4; r++) {
        const long idx = (long)(rowBase + r) * N + col;
        const float val = acc[m][n][r];
        if (EPI == EP_ADD)       xres[idx] += val;
        else if (EPI == EP_MULADD) xres[idx] = fmaf(bf16_to_f32(rr[idx]), val, xres[idx]);
      }
    }
  }
}

extern "C" void kernel_launch(void* const* d_in, const int* in_sizes, int n_in,
                              void* d_out, int out_size, void* d_ws, size_t ws_size,
                              hipStream_t stream)
{
  const float* x_in       = (const float*)d_in[0];
  const float* ln0_w      = (const float*)d_in[1];
  const float* ln0_b      = (const float*)d_in[2];
  const float* ln1_w      = (const float*)d_in[3];
  const float* ln1_b      = (const float*)d_in[4];
  const float* ln2_w      = (const float*)d_in[5];
  const float* ln2_b      = (const float*)d_in[6];
  const float* time_decay = (const float*)d_in[7];
  const float* time_first = (const float*)d_in[8];
  const float* tmk        = (const float*)d_in[9];
  const float* tmv        = (const float*)d_in[10];
  const float* tmr        = (const float*)d_in[11];
  const float* Wk         = (const float*)d_in[12];
  const float* Wv         = (const float*)d_in[13];
  const float* Wr         = (const float*)d_in[14];
  const float* Wo         = (const float*)d_in[15];
  const float* cmk        = (const float*)d_in[16];
  const float* cmr        = (const float*)d_in[17];
  const float* Wck        = (const float*)d_in[18];
  const float* Wcv        = (const float*)d_in[19];
  const float* Wcr        = (const float*)d_in[20];
  float* x = (float*)d_out;

  const int M = 4 * TT;                 // 8192 rows
  const long lCC = (long)CCH * CCH;
  const long lFC = (long)FFD * CCH;
  const long MC  = (long)M * CCH;

  unsigned short* wsl  = (unsigned short*)d_ws;
  unsigned short* wkb  = wsl;
  unsigned short* wvb  = wkb + lCC;
  unsigned short* wrb  = wvb + lCC;
  unsigned short* wob  = wrb + lCC;
  unsigned short* wcrb = wob + lCC;
  unsigned short* wckb = wcrb + lCC;
  unsigned short* wcvb = wckb + lFC;
  unsigned short* xk   = wcvb + lFC;
  unsigned short* xv   = xk + MC;
  unsigned short* xr   = xv + MC;
  unsigned short* kbuf = xr + MC;       // region reused as kf [M,F]
  unsigned short* vbuf = kbuf + MC;
  unsigned short* sbuf = vbuf + MC;
  unsigned short* kfb  = kbuf;
  unsigned short* rrb  = kbuf + (long)M * FFD;

  // WKV scan state in the (dead between GEMMs) xk region
  float* sta = (float*)xk;
  float* stb = sta + (long)NCHK * 4096;
  float* stp = stb + (long)NCHK * 4096;

  ln0_kernel<<<M, 256, 0, stream>>>(x_in, ln0_w, ln0_b, x);

  const dim3 gkvr(M / 256, CCH / 128, 3);  // (32, 8, 3)  = 768 blocks, BMt=256
  const dim3 g1  (M / 128, CCH / 128);     // (64, 8)     = 512 blocks, gemm2p
  const dim3 gffn(M / 256, FFD / 128, 2);  // (32, 32, 2), BMt=256; z1 = r sigmoid (bn<8)
  const dim3 gw(CCH / 256, NCHK, 4);       // (4, 32, 4)
  const dim3 gfuse(M, 8);                  // y0 = ln_mix<3>, y1..7 = cvt segs

  for (int l = 0; l < 4; l++) {
    CvtArgs ca;
    ca.s[0] = Wk  + (long)l * lCC; ca.d[0] = wkb;  ca.n4[0] = (int)(lCC / 4);
    ca.s[1] = Wv  + (long)l * lCC; ca.d[1] = wvb;  ca.n4[1] = (int)(lCC / 4);
    ca.s[2] = Wr  + (long)l * lCC; ca.d[2] = wrb;  ca.n4[2] = (int)(lCC / 4);
    ca.s[3] = Wo  + (long)l * lCC; ca.d[3] = wob;  ca.n4[3] = (int)(lCC / 4);
    ca.s[4] = Wcr + (long)l * lCC; ca.d[4] = wcrb; ca.n4[4] = (int)(lCC / 4);
    ca.s[5] = Wck + (long)l * lFC; ca.d[5] = wckb; ca.n4[5] = (int)(lFC / 4);
    ca.s[6] = Wcv + (long)l * lFC; ca.d[6] = wcvb; ca.n4[6] = (int)(lFC / 4);

    const float* td_l = time_decay + l*CCH;
    const float* tf_l = time_first + l*CCH;

    // --- TimeMix ---  (cvt fused with ln_mix<3>)
    lnmix3_cvt<<<gfuse, 256, 0, stream>>>(ca, x, ln1_w + l*CCH, ln1_b + l*CCH,
                                          tmk + l*CCH, tmv + l*CCH, tmr + l*CCH, xk, xv, xr);
    gemm_bt<EP_KVR, 256><<<gkvr, 256, 0, stream>>>(xk, wkb, CCH, CCH, kbuf, nullptr,
                                              nullptr, nullptr, nullptr, nullptr, 0);
    wkv_pass1 <<<gw, 256, 0, stream>>>(kbuf, vbuf, td_l, sta, stb, stp);
    wkv_pass2 <<<gw, 256, 0, stream>>>(kbuf, vbuf, sbuf, td_l, tf_l, sta, stb, stp, xv);
    gemm2p<EP_ADD><<<g1, 256, 0, stream>>>(xv, wob, CCH, CCH, x, nullptr);

    // --- ChannelMix ---
    ln_mix<2><<<M, 256, 0, stream>>>(x, ln2_w + l*CCH, ln2_b + l*CCH,
                                     cmk + l*CCH, nullptr, cmr + l*CCH, xk, nullptr, xr);
    gemm_bt<EP_FFN1, 256><<<gffn, 256, 0, stream>>>(xk, wckb, FFD, CCH, kfb, nullptr,
                                               nullptr, xr, wcrb, rrb, CCH);
    gemm2p<EP_MULADD><<<g1, 256, 0, stream>>>(kfb, wcvb, CCH, FFD, x, rrb);
  }
}